// Round 14
// baseline (237.081 us; speedup 1.0000x reference)
//
#include <hip/hip_runtime.h>
#include <hip/hip_cooperative_groups.h>
#include <cstdint>
#include <cstddef>

namespace cg = cooperative_groups;

// Problem constants (fixed by setup_inputs)
#define SEQ     43008
#define LASTOFF 10240      // L2 + L1 = 2048 + 8192
#define NV      17         // NUM_VOCAB + 1

typedef __bf16 bf16x8 __attribute__((ext_vector_type(8)));
typedef float  f32x4  __attribute__((ext_vector_type(4)));

typedef __attribute__((address_space(1))) const void gv_t;
typedef __attribute__((address_space(3))) void       lv_t;

__device__ __forceinline__ ushort f2bf(float f) {
    union { float f; unsigned u; } x; x.f = f;
    unsigned r = x.u + 0x7FFFu + ((x.u >> 16) & 1u);   // RNE
    return (ushort)(r >> 16);
}
__device__ __forceinline__ float bf2f(ushort h) {
    union { unsigned u; float f; } x; x.u = ((unsigned)h) << 16;
    return x.f;
}

// ---------------------------------------------------------------------------
// Stage a [nch*8 rows][64 bf16] tile from row-major bf16 src (row stride 256
// elems) into LDS via global_load_lds(16B). LDS layout is XOR-swizzled
// (byte ^= (row&7)<<4); the LDS dest is linear, so we pre-swizzle the per-lane
// GLOBAL source column (m173). Chunks (8 rows = 1 KB) split across nwv waves.
// ---------------------------------------------------------------------------
__device__ __forceinline__ void stage_tile_w(char* ldsbase, const ushort* src,
                                             int row0, int k0, int nch, int wv,
                                             int nwv, int lane)
{
    int sub  = lane >> 3;                 // row within chunk 0..7
    int col8 = (lane & 7) ^ sub;          // pre-swizzled 16B-slot index
    const ushort* g0 = src + (size_t)(row0 + sub) * 256 + k0 + (col8 << 3);
    for (int ch = wv; ch < nch; ch += nwv) {
        const ushort* g = g0 + ((size_t)(ch << 3)) * 256;
        __builtin_amdgcn_global_load_lds((gv_t*)g, (lv_t*)(ldsbase + (ch << 10)), 16, 0, 0);
    }
}

// Read one 16(rows)x32(k) bf16 MFMA operand fragment from a swizzled LDS tile
// with row stride 64 bf16 (128 B). lane l -> row row+(l&15), k = kk+(l>>4)*8.
__device__ __forceinline__ bf16x8 frag64(const char* lds, int row, int kk, int lane) {
    int r = row + (lane & 15);
    int byte = (r << 7) + ((kk + ((lane >> 4) << 3)) << 1);
    byte ^= (r & 7) << 4;
    return *(const bf16x8*)(lds + byte);
}

// ===========================================================================
// Phase bodies (shared by the cooperative mega-kernel and the fallback
// kernels — bit-identical behavior by construction). All verified r12 logic.
// ===========================================================================

// P1 virtual block b in [0,656)
__device__ __forceinline__ void phase_prep(int b, char* sm, int tid,
    const float* x, const float* W2, const float* W1, const float* W0,
    const float* lin_w, const int* value, const float* emb,
    const float* b0, const float* lin_b,
    ushort* xb, ushort* Wb2T, ushort* W1n, ushort* W0n,
    int* dest2, int* packT, int* cnt1, float* embLp)
{
    if (b < 192) {
        int s   = b >> 6;
        int rem = b & 63;
        int i0  = (rem >> 3) << 5;
        int o0  = (rem & 7) << 5;
        const float* W = (s == 0) ? W2 : ((s == 1) ? W1 : W0);
        float* tl = (float*)sm;
        #pragma unroll
        for (int q = 0; q < 8; ++q) {
            int fid = (q << 8) + tid;
            int ri  = fid >> 6;
            int f   = (fid & 63) << 2;
            float4 v = *(const float4*)(W + (size_t)(i0 + ri) * 2048 + o0 * 8 + f);
            int ol = f >> 3;
            int c0 = f & 7;
            tl[((c0 + 0) * 32 + ol) * 33 + ri] = v.x;
            tl[((c0 + 1) * 32 + ol) * 33 + ri] = v.y;
            tl[((c0 + 2) * 32 + ol) * 33 + ri] = v.z;
            tl[((c0 + 3) * 32 + ol) * 33 + ri] = v.w;
        }
        __syncthreads();
        int seg = tid & 3;
        if (s >= 1) {
            ushort* Wn = (s == 1) ? W1n : W0n;
            #pragma unroll
            for (int it = 0; it < 4; ++it) {
                int rk = (it << 6) + (tid >> 2);
                int c = rk >> 5, ii = rk & 31;
                ushort v8[8];
                #pragma unroll
                for (int u = 0; u < 8; ++u)
                    v8[u] = f2bf(tl[(c * 32 + (seg << 3) + u) * 33 + ii]);
                *(int4*)(Wn + (c << 16) + (i0 + ii) * 256 + o0 + (seg << 3)) =
                    *(const int4*)v8;
            }
        } else {
            #pragma unroll
            for (int it = 0; it < 4; ++it) {
                int rk = (it << 6) + (tid >> 2);   // c*32 + ol
                int j  = ((rk >> 5) << 8) + o0 + (rk & 31);
                ushort v8[8];
                #pragma unroll
                for (int u = 0; u < 8; ++u)
                    v8[u] = f2bf(tl[rk * 33 + (seg << 3) + u]);
                *(int4*)(Wb2T + ((size_t)j << 8) + i0 + (seg << 3)) =
                    *(const int4*)v8;
            }
        }
    } else if (b < 448) {
        int i8 = (((b - 192) << 8) + tid) << 3;
        float4 a  = *(const float4*)(x + i8);
        float4 bb = *(const float4*)(x + i8 + 4);
        ushort v[8] = { f2bf(a.x), f2bf(a.y), f2bf(a.z), f2bf(a.w),
                        f2bf(bb.x), f2bf(bb.y), f2bf(bb.z), f2bf(bb.w) };
        *(int4*)(xb + i8) = *(const int4*)v;
    } else if (b < 456) {
        int n    = b - 448;
        int base = n * SEQ;
        int* dst = dest2 + n * 2048;
        int cnt = 0;
        int vloc[8];
        #pragma unroll
        for (int i = 0; i < 8; ++i) {
            vloc[i] = value[base + tid * 8 + i];
            cnt += (vloc[i] == 2);
        }
        int* s = (int*)sm;
        s[tid] = cnt;
        __syncthreads();
        for (int off = 1; off < 256; off <<= 1) {
            int v = (tid >= off) ? s[tid - off] : 0;
            __syncthreads();
            s[tid] += v;
            __syncthreads();
        }
        int run = s[tid] - cnt;
        #pragma unroll
        for (int i = 0; i < 8; ++i) {
            int d = -1;
            if (vloc[i] == 2 && run < 1024) { d = run; ++run; }
            dst[tid * 8 + i] = d;
        }
    } else if (b < 464) {
        int n    = b - 456;
        int base = n * SEQ + 2048;
        int (*s8)[8] = (int(*)[8])sm;      // [256][8]
        int cnt8[8] = {0,0,0,0,0,0,0,0};
        int vloc[32];
        #pragma unroll
        for (int i = 0; i < 32; ++i) {
            vloc[i] = value[base + tid * 32 + i];
            cnt8[i & 7] += (vloc[i] == 2);
        }
        #pragma unroll
        for (int k = 0; k < 8; ++k) s8[tid][k] = cnt8[k];
        __syncthreads();
        for (int off = 1; off < 256; off <<= 1) {
            int v[8];
            #pragma unroll
            for (int k = 0; k < 8; ++k) v[k] = (tid >= off) ? s8[tid - off][k] : 0;
            __syncthreads();
            #pragma unroll
            for (int k = 0; k < 8; ++k) s8[tid][k] += v[k];
            __syncthreads();
        }
        int runK[8], runTot = 0;
        #pragma unroll
        for (int k = 0; k < 8; ++k) { runK[k] = s8[tid][k] - cnt8[k]; runTot += runK[k]; }
        #pragma unroll
        for (int i = 0; i < 32; ++i) {
            if (vloc[i] == 2) {
                int k  = i & 7;
                int tp = (tid * 32 + i) >> 3;
                packT[(((n << 3) + k) << 10) + runK[k]] = (runTot << 16) | tp;
                runK[k]++; runTot++;
            }
        }
        if (tid < 8) cnt1[(n << 3) + tid] = s8[255][tid];
    } else {
        int idx = b - 464;
        int jd  = idx >> 6;
        int p   = idx & 63;
        float* er = (float*)sm;           // 256
        float* ps = er + 256;             // 136
        float e = emb[jd * 16384 + p * 256 + tid];
        if (jd == 0) e += b0[tid];
        er[tid] = e;
        __syncthreads();
        if (tid < 136) {
            int v = tid >> 3, part = tid & 7;
            const float* lw = lin_w + v;
            float s = 0.f;
            int o0 = part << 5;
            #pragma unroll 8
            for (int o = o0; o < o0 + 32; ++o)
                s = fmaf(er[o], lw[o * NV], s);
            ps[tid] = s;
        }
        __syncthreads();
        if (tid < 20) {
            float acc = 0.f;
            if (tid < NV) {
                #pragma unroll
                for (int q = 0; q < 8; ++q) acc += ps[tid * 8 + q];
                if (jd == 0) acc += lin_b[tid];
            }
            embLp[jd * 1280 + p * 20 + tid] = acc;
        }
    }
}

// P2 virtual block vb in [0,320): [0,256) gemm2, [256,320) G/H/K1
__device__ __forceinline__ void phase_g2h(int vb, char* smem, int tid,
    int lane, int wv,
    const ushort* xb, const ushort* Wb2T, const float* b2,
    const int* dest2, ushort* x1b,
    const ushort* W0n, const float* lin_w, const ushort* W1n,
    const float* b1, ushort* Hf, float* K1f)
{
    if (vb < 256) {
        // ---------------- gemm2 (verified) ----------------
        const int r0 = (vb & 15) << 7;
        const int c0 = (vb >> 4) << 7;
        const int wm = (wv >> 1) << 6;
        const int wn = (wv & 1) << 6;

        f32x4 acc[4][4] = {};

        stage_tile_w(smem,         xb,   r0, 0, 16, wv, 4, lane);
        stage_tile_w(smem + 16384, Wb2T, c0, 0, 16, wv, 4, lane);
        __syncthreads();

        for (int kt = 0; kt < 4; ++kt) {
            char* cb = smem + ((kt & 1) << 15);
            if (kt < 3) {
                char* nb = smem + (((kt + 1) & 1) << 15);
                int k0n = (kt + 1) << 6;
                stage_tile_w(nb,         xb,   r0, k0n, 16, wv, 4, lane);
                stage_tile_w(nb + 16384, Wb2T, c0, k0n, 16, wv, 4, lane);
            }
            #pragma unroll
            for (int ks = 0; ks < 2; ++ks) {
                int kk = ks << 5;
                bf16x8 af[4], bfr[4];
                #pragma unroll
                for (int i = 0; i < 4; ++i) af[i]  = frag64(cb, wm + i * 16, kk, lane);
                #pragma unroll
                for (int i = 0; i < 4; ++i) bfr[i] = frag64(cb + 16384, wn + i * 16, kk, lane);
                #pragma unroll
                for (int mi = 0; mi < 4; ++mi)
                    #pragma unroll
                    for (int ni = 0; ni < 4; ++ni)
                        acc[mi][ni] = __builtin_amdgcn_mfma_f32_16x16x32_bf16(
                            af[mi], bfr[ni], acc[mi][ni], 0, 0, 0);
            }
            __syncthreads();
        }

        const int obase = c0 & 255;
        const int cdx   = c0 >> 8;
        float bv[4];
        #pragma unroll
        for (int ni = 0; ni < 4; ++ni)
            bv[ni] = b2[obase + wn + ni * 16 + (lane & 15)];

        ushort* Cs = (ushort*)smem;
        #pragma unroll
        for (int mi = 0; mi < 4; ++mi)
            #pragma unroll
            for (int ni = 0; ni < 4; ++ni)
                #pragma unroll
                for (int r = 0; r < 4; ++r) {
                    int row = wm + mi * 16 + ((lane >> 4) << 2) + r;
                    int col = wn + ni * 16 + (lane & 15);
                    Cs[row * 136 + col] = f2bf(acc[mi][ni][r] + bv[ni]);
                }
        __syncthreads();

        for (int p = 0; p < 8; ++p) {
            int row = p * 16 + (tid >> 4);
            int gr  = r0 + row;
            int n   = gr >> 8, t = gr & 255;
            int d   = dest2[n * 2048 + t * 8 + cdx];
            if (d >= 0) {
                int4 v = *(const int4*)&Cs[row * 136 + ((tid & 15) << 3)];
                *(int4*)&x1b[(((size_t)n * 1024 + d) << 8) + obase + ((tid & 15) << 3)] = v;
            }
        }
        return;
    }

    // ---------------- G/H/K1 blocks (verified r12 logic) ----------------
    const int idx = vb - 256;     // 0..63
    const int cp  = idx >> 3, cf = idx & 7;

    ushort* Gs  = (ushort*)smem;          // 16 KB frag [32 v][64 o] x 4 kt
    char*   Bs  = smem + 16384;           // 32 KB B tile (single-buffered)
    char*   lwA = smem + 49152;           // 16 KB A-frag [32 v][64 q] x 4 kt

    for (int j = tid; j < 4096; j += 256) ((int*)lwA)[j] = 0;
    __syncthreads();
    {
        int kt = tid >> 6, kq = tid & 63;
        const float* lsrc = lin_w + tid * NV;
        #pragma unroll
        for (int v = 0; v < NV; ++v) {
            int byte = (v << 7) + (kq << 1);
            byte ^= (v & 7) << 4;
            *(ushort*)(lwA + (kt << 12) + byte) = f2bf(lsrc[v]);
        }
    }
    __syncthreads();

    // Phase A: G = lin_wT @ W0n[cf]^T
    const ushort* W0c = W0n + ((size_t)cf << 16);
    f32x4 acc[2][16];
    {
        f32x4 z = {0.f, 0.f, 0.f, 0.f};
        #pragma unroll
        for (int mi = 0; mi < 2; ++mi)
            #pragma unroll
            for (int ni = 0; ni < 16; ++ni) acc[mi][ni] = z;
    }
    for (int kt = 0; kt < 4; ++kt) {
        stage_tile_w(Bs, W0c, 0, kt << 6, 32, wv, 4, lane);
        __syncthreads();
        #pragma unroll
        for (int ks = 0; ks < 2; ++ks) {
            int kk = ks << 5;
            bf16x8 a0 = frag64(lwA + (kt << 12), 0,  kk, lane);
            bf16x8 a1 = frag64(lwA + (kt << 12), 16, kk, lane);
            #pragma unroll
            for (int ni = 0; ni < 16; ++ni) {
                bf16x8 bfr = frag64(Bs, ni << 4, kk, lane);
                acc[0][ni] = __builtin_amdgcn_mfma_f32_16x16x32_bf16(a0, bfr, acc[0][ni], 0, 0, 0);
                acc[1][ni] = __builtin_amdgcn_mfma_f32_16x16x32_bf16(a1, bfr, acc[1][ni], 0, 0, 0);
            }
        }
        __syncthreads();
    }

    #pragma unroll
    for (int mi = 0; mi < 2; ++mi)
        #pragma unroll
        for (int ni = 0; ni < 16; ++ni)
            #pragma unroll
            for (int r = 0; r < 4; ++r) {
                int v = (mi << 4) + ((lane >> 4) << 2) + r;
                int o = (ni << 4) + (lane & 15);
                int byte = (v << 7) + ((o & 63) << 1);
                byte ^= (v & 7) << 4;
                *(ushort*)((char*)Gs + ((o >> 6) << 12) + byte) = f2bf(acc[mi][ni][r]);
            }
    __syncthreads();

    // K1 (cp==0): K1f[cf*17+v] = sum_o b1[o] * Gs[v][o]
    if (cp == 0) {
        float bo = b1[tid];
        int kt = tid >> 6, kq = tid & 63;
        float p[NV];
        #pragma unroll
        for (int v = 0; v < NV; ++v) {
            int byte = (v << 7) + (kq << 1);
            byte ^= (v & 7) << 4;
            p[v] = bo * bf2f(*(const ushort*)((const char*)Gs + (kt << 12) + byte));
        }
        #pragma unroll
        for (int off = 32; off >= 1; off >>= 1)
            #pragma unroll
            for (int v = 0; v < NV; ++v)
                p[v] += __shfl_xor(p[v], off);
        float* Ks = (float*)lwA;
        if (lane == 0)
            #pragma unroll
            for (int v = 0; v < NV; ++v) Ks[wv * NV + v] = p[v];
        __syncthreads();
        if (tid < NV)
            K1f[cf * NV + tid] = Ks[tid] + Ks[NV + tid] + Ks[2 * NV + tid] + Ks[3 * NV + tid];
        if (cf == 7 && tid >= 136 && tid < 144) K1f[tid] = 0.f;
        __syncthreads();
    }

    // Phase C: Hf[cp][cf*17+v][i] = sum_o Gs[v][o] * W1n[cp][i][o]
    const ushort* Wb1 = W1n + ((size_t)cp << 16);
    {
        f32x4 z = {0.f, 0.f, 0.f, 0.f};
        #pragma unroll
        for (int mi = 0; mi < 2; ++mi)
            #pragma unroll
            for (int ni = 0; ni < 16; ++ni) acc[mi][ni] = z;
    }
    for (int kt = 0; kt < 4; ++kt) {
        stage_tile_w(Bs, Wb1, 0, kt << 6, 32, wv, 4, lane);
        __syncthreads();
        #pragma unroll
        for (int ks = 0; ks < 2; ++ks) {
            int kk = ks << 5;
            bf16x8 a0 = frag64((char*)Gs + (kt << 12), 0,  kk, lane);
            bf16x8 a1 = frag64((char*)Gs + (kt << 12), 16, kk, lane);
            #pragma unroll
            for (int ni = 0; ni < 16; ++ni) {
                bf16x8 bfr = frag64(Bs, ni << 4, kk, lane);
                acc[0][ni] = __builtin_amdgcn_mfma_f32_16x16x32_bf16(a0, bfr, acc[0][ni], 0, 0, 0);
                acc[1][ni] = __builtin_amdgcn_mfma_f32_16x16x32_bf16(a1, bfr, acc[1][ni], 0, 0, 0);
            }
        }
        __syncthreads();
    }

    #pragma unroll
    for (int mi = 0; mi < 2; ++mi)
        #pragma unroll
        for (int ni = 0; ni < 16; ++ni)
            #pragma unroll
            for (int r = 0; r < 4; ++r) {
                int v = (mi << 4) + ((lane >> 4) << 2) + r;
                if (v < NV) {
                    int i = (ni << 4) + (lane & 15);
                    Hf[cp * 36864 + (cf * NV + v) * 256 + i] = f2bf(acc[mi][ni][r]);
                }
            }
    if (cf == 7)
        for (int j = tid; j < 2048; j += 256)
            Hf[cp * 36864 + 136 * 256 + j] = 0;
}

// P3 virtual block vb in [0,1024): bb = vb&63 (= n*8+c'), t0 = (vb>>6)*64.
// 64 KB LDS layout: dbuf 2x26624 | epi: Cs [0,34816) fp32, embLs@36864,
// K1s@52224, Ds@52800 (tables loaded AFTER the K-loop).
__device__ __forceinline__ void phase_fused(int vb, char* smem, int tid,
    int lane, int wv,
    const ushort* x1b, const ushort* Hf, const float* embLp,
    const float* K1f, const int* packT, const int* cnt1,
    const int* pos, float* out)
{
    const int bb = vb & 63;           // n*8 + c'
    const int n  = bb >> 3, cp = bb & 7;
    const int t0 = (vb >> 6) << 6;
    const int cnt = cnt1[bb];
    if (t0 >= cnt) return;
    const int cntL = min(64, cnt - t0);

    const int sub  = lane >> 3;
    const int col8 = (lane & 7) ^ sub;
    const int* pbase = packT + (bb << 10);
    int Ta = pbase[t0 + (wv << 3) + sub] & 1023;
    int Tb = pbase[t0 + ((wv + 4) << 3) + sub] & 1023;
    const ushort* ga0 = x1b + ((size_t)((n << 10) + Ta) << 8) + (col8 << 3);
    const ushort* gb0 = x1b + ((size_t)((n << 10) + Tb) << 8) + (col8 << 3);

    const ushort* Hb = Hf + cp * 36864;

    __builtin_amdgcn_global_load_lds((gv_t*)ga0, (lv_t*)(smem + (wv << 10)), 16, 0, 0);
    __builtin_amdgcn_global_load_lds((gv_t*)gb0, (lv_t*)(smem + ((wv + 4) << 10)), 16, 0, 0);
    stage_tile_w(smem + 8192, Hb, 0, 0, 18, wv, 4, lane);
    __syncthreads();

    f32x4 acc[9] = {};
    for (int kt = 0; kt < 4; ++kt) {
        char* cb = smem + (kt & 1) * 26624;
        if (kt < 3) {
            char* nb = smem + ((kt + 1) & 1) * 26624;
            int k0n = (kt + 1) << 6;
            __builtin_amdgcn_global_load_lds((gv_t*)(ga0 + k0n), (lv_t*)(nb + (wv << 10)), 16, 0, 0);
            __builtin_amdgcn_global_load_lds((gv_t*)(gb0 + k0n), (lv_t*)(nb + ((wv + 4) << 10)), 16, 0, 0);
            stage_tile_w(nb + 8192, Hb, 0, k0n, 18, wv, 4, lane);
        }
        #pragma unroll
        for (int ks = 0; ks < 2; ++ks) {
            int kk = ks << 5;
            bf16x8 af = frag64(cb, wv << 4, kk, lane);
            #pragma unroll
            for (int ni = 0; ni < 9; ++ni) {
                bf16x8 bfr = frag64(cb + 8192, ni << 4, kk, lane);
                acc[ni] = __builtin_amdgcn_mfma_f32_16x16x32_bf16(af, bfr, acc[ni], 0, 0, 0);
            }
        }
        __syncthreads();
    }

    // acc -> Cs [64][136] fp32 @0; tables at 36864+ (post-loop load)
    float* Cs = (float*)smem;
    #pragma unroll
    for (int ni = 0; ni < 9; ++ni) {
        int col = (ni << 4) + (lane & 15);
        if (col < 136) {
            #pragma unroll
            for (int r = 0; r < 4; ++r) {
                int row = (wv << 4) + ((lane >> 4) << 2) + r;
                Cs[row * 136 + col] = acc[ni][r];
            }
        }
    }
    float* embLs = (float*)(smem + 36864);
    for (int i = tid; i < 3840; i += 256) embLs[i] = embLp[i];
    float* K1s = (float*)(smem + 52224);
    if (tid < 144) K1s[tid] = K1f[tid];
    int* Ds = (int*)(smem + 52800);
    if (tid < 64) Ds[tid] = (pbase[t0 + tid] >> 16) & 4095;
    __syncthreads();

    #pragma unroll
    for (int rr = 0; rr < 2; ++rr) {
        int rl = tid * 2 + rr;
        int r  = rl >> 3, c = rl & 7;
        int prow = n * SEQ + LASTOFF + (Ds[r] << 3) + c;
        const int* pp = pos + 3 * prow;
        const float* e0 = embLs +        pp[0] * 20;
        const float* e1 = embLs + 1280 + pp[1] * 20;
        const float* e2 = embLs + 2560 + pp[2] * 20;
        const float* k1 = K1s + c * 17;
        float* cr = Cs + rl * 17;
        #pragma unroll
        for (int v4 = 0; v4 < 16; v4 += 4) {
            float4 a = *(const float4*)(e0 + v4);
            float4 bq = *(const float4*)(e1 + v4);
            float4 cq = *(const float4*)(e2 + v4);
            cr[v4 + 0] += a.x + bq.x + cq.x + k1[v4 + 0];
            cr[v4 + 1] += a.y + bq.y + cq.y + k1[v4 + 1];
            cr[v4 + 2] += a.z + bq.z + cq.z + k1[v4 + 2];
            cr[v4 + 3] += a.w + bq.w + cq.w + k1[v4 + 3];
        }
        cr[16] += e0[16] + e1[16] + e2[16] + k1[16];
    }
    __syncthreads();

    for (int i4 = tid; i4 < 2176; i4 += 256) {
        int r  = (i4 * 1928) >> 16;        // i4 / 34
        int fo = i4 - r * 34;
        if (r < cntL) {
            *(float4*)(out + ((size_t)((n << 12) + Ds[r])) * 136 + (fo << 2)) =
                *(const float4*)(Cs + r * 136 + (fo << 2));
        }
    }
}

// ===========================================================================
// Cooperative mega-kernel: any grid size (loops stride by gridDim.x).
// ===========================================================================
__global__ __launch_bounds__(256, 2) void mega(
    const float* __restrict__ x, const float* __restrict__ W2,
    const float* __restrict__ W1, const float* __restrict__ W0,
    const float* __restrict__ lin_w, const int* __restrict__ value,
    const float* __restrict__ emb, const float* __restrict__ b0,
    const float* __restrict__ lin_b, const float* __restrict__ b1,
    const float* __restrict__ b2, const int* __restrict__ pos,
    ushort* __restrict__ xb, ushort* __restrict__ Wb2T,
    ushort* __restrict__ W1n, ushort* __restrict__ W0n,
    int* __restrict__ dest2, int* __restrict__ packT,
    int* __restrict__ cnt1, float* __restrict__ embLp,
    ushort* __restrict__ x1b, ushort* __restrict__ Hf,
    float* __restrict__ K1f, float* __restrict__ out)
{
    extern __shared__ __align__(16) char smem[];   // 65536
    cg::grid_group grid = cg::this_grid();
    const int tid  = threadIdx.x;
    const int lane = tid & 63, wv = tid >> 6;

    for (int b = blockIdx.x; b < 656; b += gridDim.x) {
        __syncthreads();
        phase_prep(b, smem, tid, x, W2, W1, W0, lin_w, value, emb, b0, lin_b,
                   xb, Wb2T, W1n, W0n, dest2, packT, cnt1, embLp);
    }
    __threadfence();
    grid.sync();

    for (int vb = blockIdx.x; vb < 320; vb += gridDim.x) {
        __syncthreads();
        phase_g2h(vb, smem, tid, lane, wv, xb, Wb2T, b2, dest2, x1b,
                  W0n, lin_w, W1n, b1, Hf, K1f);
    }
    __threadfence();
    grid.sync();

    for (int vb = blockIdx.x; vb < 1024; vb += gridDim.x) {
        __syncthreads();
        phase_fused(vb, smem, tid, lane, wv, x1b, Hf, embLp, K1f,
                    packT, cnt1, pos, out);
    }
}

// ===========================================================================
// Fallback kernels (3-node pipeline) — thin wrappers over the same bodies.
// ===========================================================================
__global__ __launch_bounds__(256) void prep_k(
    const float* x, const float* W2, const float* W1, const float* W0,
    const float* lin_w, const int* value, const float* emb,
    const float* b0, const float* lin_b,
    ushort* xb, ushort* Wb2T, ushort* W1n, ushort* W0n,
    int* dest2, int* packT, int* cnt1, float* embLp)
{
    __shared__ __align__(16) char sm[33792];
    phase_prep(blockIdx.x, sm, threadIdx.x, x, W2, W1, W0, lin_w, value, emb,
               b0, lin_b, xb, Wb2T, W1n, W0n, dest2, packT, cnt1, embLp);
}

__global__ __launch_bounds__(256) void g2h_k(
    const ushort* xb, const ushort* Wb2T, const float* b2,
    const int* dest2, ushort* x1b,
    const ushort* W0n, const float* lin_w, const ushort* W1n,
    const float* b1, ushort* Hf, float* K1f)
{
    extern __shared__ __align__(16) char smem[];
    phase_g2h(blockIdx.x, smem, threadIdx.x, threadIdx.x & 63, threadIdx.x >> 6,
              xb, Wb2T, b2, dest2, x1b, W0n, lin_w, W1n, b1, Hf, K1f);
}

__global__ __launch_bounds__(256) void fused_k(
    const ushort* x1b, const ushort* Hf, const float* embLp,
    const float* K1f, const int* packT, const int* cnt1,
    const int* pos, float* out)
{
    extern __shared__ __align__(16) char smem[];
    phase_fused(blockIdx.x, smem, threadIdx.x, threadIdx.x & 63, threadIdx.x >> 6,
                x1b, Hf, embLp, K1f, packT, cnt1, pos, out);
}

// ---------------------------------------------------------------------------
extern "C" void kernel_launch(void* const* d_in, const int* in_sizes, int n_in,
                              void* d_out, int out_size, void* d_ws, size_t ws_size,
                              hipStream_t stream)
{
    (void)in_sizes; (void)n_in; (void)out_size; (void)ws_size;
    const float* x     = (const float*)d_in[0];
    const int*   value = (const int*)d_in[1];
    const int*   pos   = (const int*)d_in[3];
    const float* W2    = (const float*)d_in[4];
    const float* b2    = (const float*)d_in[5];
    const float* W1    = (const float*)d_in[6];
    const float* b1    = (const float*)d_in[7];
    const float* W0    = (const float*)d_in[8];
    const float* b0    = (const float*)d_in[9];
    const float* emb   = (const float*)d_in[10];
    const float* lin_w = (const float*)d_in[11];
    const float* lin_b = (const float*)d_in[12];
    float* out = (float*)d_out;

    char* ws = (char*)d_ws;
    ushort* Wb2T  = (ushort*)(ws);                  // 1 MB
    ushort* W0n   = (ushort*)(ws + 2097152);        // 1 MB
    ushort* W1n   = (ushort*)(ws + 3145728);        // 1 MB
    ushort* xb    = (ushort*)(ws + 4194304);        // 1 MB
    int*    dest2 = (int*)   (ws + 5242880);        // 16384 ints
    int*    cnt1  = (int*)   (ws + 5308416);        // 64 ints
    int*    packT = (int*)   (ws + 5308672);        // 64*1024 ints = 256 KB
    ushort* x1b   = (ushort*)(ws + 5570816);        // 4 MB
    float*  embLp = (float*) (ws + 9838848);        // 3840 fp32
    ushort* Hf    = (ushort*)(ws + 9854208);        // 576 KB
    float*  K1f   = (float*) (ws + 10444032);       // 144 fp32
    // total ~10.4 MB

    // --- attempt cooperative single-kernel launch with adaptive grid ---
    bool launched = false;
    int nb = 0, ncu = 0, dev = 0;
    hipError_t e0 = hipGetDevice(&dev);
    hipError_t e1 = hipDeviceGetAttribute(&ncu, hipDeviceAttributeMultiprocessorCount, dev);
    hipError_t e2 = hipOccupancyMaxActiveBlocksPerMultiprocessor(
        &nb, (const void*)mega, 256, (size_t)65536);
    if (e0 == hipSuccess && e1 == hipSuccess && e2 == hipSuccess &&
        nb >= 1 && ncu >= 1) {
        long cap = (long)nb * (long)ncu;
        int grid = (int)(cap < 512 ? cap : 512);
        void* args[] = {
            (void*)&x, (void*)&W2, (void*)&W1, (void*)&W0, (void*)&lin_w,
            (void*)&value, (void*)&emb, (void*)&b0, (void*)&lin_b, (void*)&b1,
            (void*)&b2, (void*)&pos,
            (void*)&xb, (void*)&Wb2T, (void*)&W1n, (void*)&W0n,
            (void*)&dest2, (void*)&packT, (void*)&cnt1, (void*)&embLp,
            (void*)&x1b, (void*)&Hf, (void*)&K1f, (void*)&out
        };
        hipError_t le = hipLaunchCooperativeKernel((const void*)mega, dim3(grid),
                                                   dim3(256), args, 65536, stream);
        if (le == hipSuccess) launched = true;
        else (void)hipGetLastError();   // clear latched error
    } else {
        (void)hipGetLastError();
    }

    if (!launched) {
        // --- fallback: 3-node pipeline (identical phase bodies) ---
        prep_k<<<656, 256, 0, stream>>>(x, W2, W1, W0, lin_w, value, emb,
                                        b0, lin_b, xb, Wb2T, W1n, W0n,
                                        dest2, packT, cnt1, embLp);
        g2h_k<<<320, 256, 65536, stream>>>(xb, Wb2T, b2, dest2, x1b,
                                           W0n, lin_w, W1n, b1, Hf, K1f);
        fused_k<<<1024, 256, 65536, stream>>>(x1b, Hf, embLp, K1f,
                                              packT, cnt1, pos, out);
    }
}

// Round 15
// 56.101 us; speedup vs baseline: 4.2260x; 4.2260x over previous
//
#include <hip/hip_runtime.h>
#include <cstdint>
#include <cstddef>

// Problem constants (fixed by setup_inputs)
#define SEQ     43008
#define LASTOFF 10240      // L2 + L1 = 2048 + 8192
#define NV      17         // NUM_VOCAB + 1

typedef __bf16 bf16x8 __attribute__((ext_vector_type(8)));
typedef float  f32x4  __attribute__((ext_vector_type(4)));

typedef __attribute__((address_space(1))) const void gv_t;
typedef __attribute__((address_space(3))) void       lv_t;

__device__ __forceinline__ ushort f2bf(float f) {
    union { float f; unsigned u; } x; x.f = f;
    unsigned r = x.u + 0x7FFFu + ((x.u >> 16) & 1u);   // RNE
    return (ushort)(r >> 16);
}
__device__ __forceinline__ float bf2f(ushort h) {
    union { unsigned u; float f; } x; x.u = ((unsigned)h) << 16;
    return x.f;
}

// ---------------------------------------------------------------------------
// Stage a [nch*8 rows][64 bf16] tile from row-major bf16 src (row stride 256
// elems) into LDS via global_load_lds(16B). LDS layout is XOR-swizzled
// (byte ^= (row&7)<<4); the LDS dest is linear, so we pre-swizzle the per-lane
// GLOBAL source column (m173). Chunks (8 rows = 1 KB) split across nwv waves.
// ---------------------------------------------------------------------------
__device__ __forceinline__ void stage_tile_w(char* ldsbase, const ushort* src,
                                             int row0, int k0, int nch, int wv,
                                             int nwv, int lane)
{
    int sub  = lane >> 3;                 // row within chunk 0..7
    int col8 = (lane & 7) ^ sub;          // pre-swizzled 16B-slot index
    const ushort* g0 = src + (size_t)(row0 + sub) * 256 + k0 + (col8 << 3);
    for (int ch = wv; ch < nch; ch += nwv) {
        const ushort* g = g0 + ((size_t)(ch << 3)) * 256;
        __builtin_amdgcn_global_load_lds((gv_t*)g, (lv_t*)(ldsbase + (ch << 10)), 16, 0, 0);
    }
}

// Read one 16(rows)x32(k) bf16 MFMA operand fragment from a swizzled LDS tile
// with row stride 64 bf16 (128 B). lane l -> row row+(l&15), k = kk+(l>>4)*8.
__device__ __forceinline__ bf16x8 frag64(const char* lds, int row, int kk, int lane) {
    int r = row + (lane & 15);
    int byte = (r << 7) + ((kk + ((lane >> 4) << 3)) << 1);
    byte ^= (r & 7) << 4;
    return *(const bf16x8*)(lds + byte);
}

// ---------------------------------------------------------------------------
// Merged prep (656 blocks) — verified r12 logic, unchanged:
//   [0,192)    W transpose via LDS tile: s==0 -> Wb2T[c*256+o][i]; s==1 ->
//              W1n[c][i][o]; s==2 -> W0n[c][i][o]. Coalesced loads AND stores.
//   [192,448)  conv_x
//   [448,456)  build_dest seg2
//   [456,464)  bucket builder seg1
//   [464,656)  embL
// ---------------------------------------------------------------------------
__global__ __launch_bounds__(256) void prep_main(
    const float* __restrict__ x, const float* __restrict__ W2,
    const float* __restrict__ W1, const float* __restrict__ W0,
    const float* __restrict__ lin_w, const int* __restrict__ value,
    const float* __restrict__ emb, const float* __restrict__ b0,
    const float* __restrict__ lin_b,
    ushort* __restrict__ xb, ushort* __restrict__ Wb2T,
    ushort* __restrict__ W1n, ushort* __restrict__ W0n,
    int* __restrict__ dest2,
    int* __restrict__ packT, int* __restrict__ cnt1,
    float* __restrict__ embLp)
{
    __shared__ __align__(16) char sm[33792];   // transpose tile [8][32][33] fp32
    const int b = blockIdx.x;
    const int tid = threadIdx.x;

    if (b < 192) {
        int s   = b >> 6;
        int rem = b & 63;
        int i0  = (rem >> 3) << 5;
        int o0  = (rem & 7) << 5;
        const float* W = (s == 0) ? W2 : ((s == 1) ? W1 : W0);
        float* tl = (float*)sm;
        #pragma unroll
        for (int q = 0; q < 8; ++q) {
            int fid = (q << 8) + tid;
            int ri  = fid >> 6;
            int f   = (fid & 63) << 2;
            float4 v = *(const float4*)(W + (size_t)(i0 + ri) * 2048 + o0 * 8 + f);
            int ol = f >> 3;
            int c0 = f & 7;
            tl[((c0 + 0) * 32 + ol) * 33 + ri] = v.x;
            tl[((c0 + 1) * 32 + ol) * 33 + ri] = v.y;
            tl[((c0 + 2) * 32 + ol) * 33 + ri] = v.z;
            tl[((c0 + 3) * 32 + ol) * 33 + ri] = v.w;
        }
        __syncthreads();
        int seg = tid & 3;
        if (s >= 1) {
            // i-major: Wn[c][i][o] (o-contiguous)
            ushort* Wn = (s == 1) ? W1n : W0n;
            #pragma unroll
            for (int it = 0; it < 4; ++it) {
                int rk = (it << 6) + (tid >> 2);
                int c = rk >> 5, ii = rk & 31;
                ushort v8[8];
                #pragma unroll
                for (int u = 0; u < 8; ++u)
                    v8[u] = f2bf(tl[(c * 32 + (seg << 3) + u) * 33 + ii]);
                *(int4*)(Wn + (c << 16) + (i0 + ii) * 256 + o0 + (seg << 3)) =
                    *(const int4*)v8;
            }
        } else {
            // j-major: Wb2T[c*256+o][i]
            #pragma unroll
            for (int it = 0; it < 4; ++it) {
                int rk = (it << 6) + (tid >> 2);   // c*32 + ol
                int j  = ((rk >> 5) << 8) + o0 + (rk & 31);
                ushort v8[8];
                #pragma unroll
                for (int u = 0; u < 8; ++u)
                    v8[u] = f2bf(tl[rk * 33 + (seg << 3) + u]);
                *(int4*)(Wb2T + ((size_t)j << 8) + i0 + (seg << 3)) =
                    *(const int4*)v8;
            }
        }
    } else if (b < 448) {
        int i8 = (((b - 192) << 8) + tid) << 3;
        float4 a  = *(const float4*)(x + i8);
        float4 bb = *(const float4*)(x + i8 + 4);
        ushort v[8] = { f2bf(a.x), f2bf(a.y), f2bf(a.z), f2bf(a.w),
                        f2bf(bb.x), f2bf(bb.y), f2bf(bb.z), f2bf(bb.w) };
        *(int4*)(xb + i8) = *(const int4*)v;
    } else if (b < 456) {
        int n    = b - 448;
        int base = n * SEQ;
        int* dst = dest2 + n * 2048;
        int cnt = 0;
        int vloc[8];
        #pragma unroll
        for (int i = 0; i < 8; ++i) {
            vloc[i] = value[base + tid * 8 + i];
            cnt += (vloc[i] == 2);
        }
        int* s = (int*)sm;
        s[tid] = cnt;
        __syncthreads();
        for (int off = 1; off < 256; off <<= 1) {
            int v = (tid >= off) ? s[tid - off] : 0;
            __syncthreads();
            s[tid] += v;
            __syncthreads();
        }
        int run = s[tid] - cnt;
        #pragma unroll
        for (int i = 0; i < 8; ++i) {
            int d = -1;
            if (vloc[i] == 2 && run < 1024) { d = run; ++run; }
            dst[tid * 8 + i] = d;
        }
    } else if (b < 464) {
        int n    = b - 456;
        int base = n * SEQ + 2048;
        int (*s8)[8] = (int(*)[8])sm;      // [256][8]
        int cnt8[8] = {0,0,0,0,0,0,0,0};
        int vloc[32];
        #pragma unroll
        for (int i = 0; i < 32; ++i) {
            vloc[i] = value[base + tid * 32 + i];
            cnt8[i & 7] += (vloc[i] == 2);
        }
        #pragma unroll
        for (int k = 0; k < 8; ++k) s8[tid][k] = cnt8[k];
        __syncthreads();
        for (int off = 1; off < 256; off <<= 1) {
            int v[8];
            #pragma unroll
            for (int k = 0; k < 8; ++k) v[k] = (tid >= off) ? s8[tid - off][k] : 0;
            __syncthreads();
            #pragma unroll
            for (int k = 0; k < 8; ++k) s8[tid][k] += v[k];
            __syncthreads();
        }
        int runK[8], runTot = 0;
        #pragma unroll
        for (int k = 0; k < 8; ++k) { runK[k] = s8[tid][k] - cnt8[k]; runTot += runK[k]; }
        #pragma unroll
        for (int i = 0; i < 32; ++i) {
            if (vloc[i] == 2) {
                int k  = i & 7;
                int tp = (tid * 32 + i) >> 3;
                packT[(((n << 3) + k) << 10) + runK[k]] = (runTot << 16) | tp;
                runK[k]++; runTot++;
            }
        }
        if (tid < 8) cnt1[(n << 3) + tid] = s8[255][tid];
    } else {
        int idx = b - 464;
        int jd  = idx >> 6;
        int p   = idx & 63;
        float* er = (float*)sm;           // 256
        float* ps = er + 256;             // 136
        float e = emb[jd * 16384 + p * 256 + tid];
        if (jd == 0) e += b0[tid];
        er[tid] = e;
        __syncthreads();
        if (tid < 136) {
            int v = tid >> 3, part = tid & 7;
            const float* lw = lin_w + v;
            float s = 0.f;
            int o0 = part << 5;
            #pragma unroll 8
            for (int o = o0; o < o0 + 32; ++o)
                s = fmaf(er[o], lw[o * NV], s);
            ps[tid] = s;
        }
        __syncthreads();
        if (tid < 20) {
            float acc = 0.f;
            if (tid < NV) {
                #pragma unroll
                for (int q = 0; q < 8; ++q) acc += ps[tid * 8 + q];
                if (jd == 0) acc += lin_b[tid];
            }
            embLp[jd * 1280 + p * 20 + tid] = acc;
        }
    }
}

// ---------------------------------------------------------------------------
// Node 2 (320 blocks, dyn LDS 65536): H FIRST (so the long H blocks overlap
// gemm2 instead of trailing it), then gemm2.
//   [0,64): block (cp, cf): G via MFMA -> Gs; K1 (cp==0); H via MFMA -> Hf.
//   [64,320): MFMA GEMM stage 2: scatter via dest2 -> x1b.
// All bodies verified r12 logic (only block-index mapping changed).
// ---------------------------------------------------------------------------
__global__ __launch_bounds__(256) void g2h(
    const ushort* __restrict__ A, const ushort* __restrict__ BT,
    const float* __restrict__ bias, const int* __restrict__ dest,
    ushort* __restrict__ Xout,
    const ushort* __restrict__ W0n, const float* __restrict__ lin_w,
    const ushort* __restrict__ W1n, const float* __restrict__ b1,
    ushort* __restrict__ Hf, float* __restrict__ K1f)
{
    extern __shared__ __align__(16) char smem[];   // 65536
    const int tid = threadIdx.x;
    const int lane = tid & 63, wv = tid >> 6;

    if (blockIdx.x >= 64) {
        // ---------------- gemm2 (verified, unchanged logic) ----------------
        const int bx = blockIdx.x - 64;
        const int r0 = (bx & 15) << 7;
        const int c0 = (bx >> 4) << 7;
        const int wm = (wv >> 1) << 6;
        const int wn = (wv & 1) << 6;

        f32x4 acc[4][4] = {};

        stage_tile_w(smem,         A,  r0, 0, 16, wv, 4, lane);
        stage_tile_w(smem + 16384, BT, c0, 0, 16, wv, 4, lane);
        __syncthreads();

        for (int kt = 0; kt < 4; ++kt) {
            char* cb = smem + ((kt & 1) << 15);
            if (kt < 3) {
                char* nb = smem + (((kt + 1) & 1) << 15);
                int k0n = (kt + 1) << 6;
                stage_tile_w(nb,         A,  r0, k0n, 16, wv, 4, lane);
                stage_tile_w(nb + 16384, BT, c0, k0n, 16, wv, 4, lane);
            }
            #pragma unroll
            for (int ks = 0; ks < 2; ++ks) {
                int kk = ks << 5;
                bf16x8 af[4], bfr[4];
                #pragma unroll
                for (int i = 0; i < 4; ++i) af[i]  = frag64(cb, wm + i * 16, kk, lane);
                #pragma unroll
                for (int i = 0; i < 4; ++i) bfr[i] = frag64(cb + 16384, wn + i * 16, kk, lane);
                #pragma unroll
                for (int mi = 0; mi < 4; ++mi)
                    #pragma unroll
                    for (int ni = 0; ni < 4; ++ni)
                        acc[mi][ni] = __builtin_amdgcn_mfma_f32_16x16x32_bf16(
                            af[mi], bfr[ni], acc[mi][ni], 0, 0, 0);
            }
            __syncthreads();
        }

        const int obase = c0 & 255;
        const int cdx   = c0 >> 8;
        float bv[4];
        #pragma unroll
        for (int ni = 0; ni < 4; ++ni)
            bv[ni] = bias[obase + wn + ni * 16 + (lane & 15)];

        ushort* Cs = (ushort*)smem;
        #pragma unroll
        for (int mi = 0; mi < 4; ++mi)
            #pragma unroll
            for (int ni = 0; ni < 4; ++ni)
                #pragma unroll
                for (int r = 0; r < 4; ++r) {
                    int row = wm + mi * 16 + ((lane >> 4) << 2) + r;
                    int col = wn + ni * 16 + (lane & 15);
                    Cs[row * 136 + col] = f2bf(acc[mi][ni][r] + bv[ni]);
                }
        __syncthreads();

        for (int p = 0; p < 8; ++p) {
            int row = p * 16 + (tid >> 4);
            int gr  = r0 + row;
            int n   = gr >> 8, t = gr & 255;
            int d   = dest[n * 2048 + t * 8 + cdx];
            if (d >= 0) {
                int4 v = *(const int4*)&Cs[row * 136 + ((tid & 15) << 3)];
                *(int4*)&Xout[(((size_t)n * 1024 + d) << 8) + obase + ((tid & 15) << 3)] = v;
            }
        }
        return;
    }

    // ---------------- H blocks (verified r12 logic, now FIRST) --------------
    const int idx = blockIdx.x;           // 0..63
    const int cp  = idx >> 3, cf = idx & 7;

    ushort* Gs  = (ushort*)smem;          // 16 KB frag [32 v][64 o] x 4 kt
    char*   Bs  = smem + 16384;           // 32 KB B tile (single-buffered)
    char*   lwA = smem + 49152;           // 16 KB A-frag [32 v][64 q] x 4 kt

    for (int j = tid; j < 4096; j += 256) ((int*)lwA)[j] = 0;
    __syncthreads();
    {
        int kt = tid >> 6, kq = tid & 63;
        const float* lsrc = lin_w + tid * NV;
        #pragma unroll
        for (int v = 0; v < NV; ++v) {
            int byte = (v << 7) + (kq << 1);
            byte ^= (v & 7) << 4;
            *(ushort*)(lwA + (kt << 12) + byte) = f2bf(lsrc[v]);
        }
    }
    __syncthreads();

    // Phase A: G = lin_wT @ W0n[cf]^T  (M=32, N=256, K=256)
    const ushort* W0c = W0n + ((size_t)cf << 16);
    f32x4 acc[2][16];
    {
        f32x4 z = {0.f, 0.f, 0.f, 0.f};
        #pragma unroll
        for (int mi = 0; mi < 2; ++mi)
            #pragma unroll
            for (int ni = 0; ni < 16; ++ni) acc[mi][ni] = z;
    }
    for (int kt = 0; kt < 4; ++kt) {
        stage_tile_w(Bs, W0c, 0, kt << 6, 32, wv, 4, lane);
        __syncthreads();
        #pragma unroll
        for (int ks = 0; ks < 2; ++ks) {
            int kk = ks << 5;
            bf16x8 a0 = frag64(lwA + (kt << 12), 0,  kk, lane);
            bf16x8 a1 = frag64(lwA + (kt << 12), 16, kk, lane);
            #pragma unroll
            for (int ni = 0; ni < 16; ++ni) {
                bf16x8 bfr = frag64(Bs, ni << 4, kk, lane);
                acc[0][ni] = __builtin_amdgcn_mfma_f32_16x16x32_bf16(a0, bfr, acc[0][ni], 0, 0, 0);
                acc[1][ni] = __builtin_amdgcn_mfma_f32_16x16x32_bf16(a1, bfr, acc[1][ni], 0, 0, 0);
            }
        }
        __syncthreads();
    }

    // acc -> Gs bf16 frag layout [v][o] (rows 17..31 are zero via A-pad)
    #pragma unroll
    for (int mi = 0; mi < 2; ++mi)
        #pragma unroll
        for (int ni = 0; ni < 16; ++ni)
            #pragma unroll
            for (int r = 0; r < 4; ++r) {
                int v = (mi << 4) + ((lane >> 4) << 2) + r;
                int o = (ni << 4) + (lane & 15);
                int byte = (v << 7) + ((o & 63) << 1);
                byte ^= (v & 7) << 4;
                *(ushort*)((char*)Gs + ((o >> 6) << 12) + byte) = f2bf(acc[mi][ni][r]);
            }
    __syncthreads();

    // K1 (cp==0 blocks): K1f[cf*17+v] = sum_o b1[o] * Gs[v][o]
    if (cp == 0) {
        float bo = b1[tid];
        int kt = tid >> 6, kq = tid & 63;
        float p[NV];
        #pragma unroll
        for (int v = 0; v < NV; ++v) {
            int byte = (v << 7) + (kq << 1);
            byte ^= (v & 7) << 4;
            p[v] = bo * bf2f(*(const ushort*)((const char*)Gs + (kt << 12) + byte));
        }
        #pragma unroll
        for (int off = 32; off >= 1; off >>= 1)
            #pragma unroll
            for (int v = 0; v < NV; ++v)
                p[v] += __shfl_xor(p[v], off);
        float* Ks = (float*)lwA;          // lwA dead after phase A
        if (lane == 0)
            #pragma unroll
            for (int v = 0; v < NV; ++v) Ks[wv * NV + v] = p[v];
        __syncthreads();
        if (tid < NV)
            K1f[cf * NV + tid] = Ks[tid] + Ks[NV + tid] + Ks[2 * NV + tid] + Ks[3 * NV + tid];
        if (cf == 7 && tid >= 136 && tid < 144) K1f[tid] = 0.f;
        __syncthreads();
    }

    // Phase C: Hf[cp][cf*17+v][i] = sum_o Gs[v][o] * W1n[cp][i][o]
    const ushort* Wb1 = W1n + ((size_t)cp << 16);
    {
        f32x4 z = {0.f, 0.f, 0.f, 0.f};
        #pragma unroll
        for (int mi = 0; mi < 2; ++mi)
            #pragma unroll
            for (int ni = 0; ni < 16; ++ni) acc[mi][ni] = z;
    }
    for (int kt = 0; kt < 4; ++kt) {
        stage_tile_w(Bs, Wb1, 0, kt << 6, 32, wv, 4, lane);
        __syncthreads();
        #pragma unroll
        for (int ks = 0; ks < 2; ++ks) {
            int kk = ks << 5;
            bf16x8 a0 = frag64((char*)Gs + (kt << 12), 0,  kk, lane);
            bf16x8 a1 = frag64((char*)Gs + (kt << 12), 16, kk, lane);
            #pragma unroll
            for (int ni = 0; ni < 16; ++ni) {
                bf16x8 bfr = frag64(Bs, ni << 4, kk, lane);
                acc[0][ni] = __builtin_amdgcn_mfma_f32_16x16x32_bf16(a0, bfr, acc[0][ni], 0, 0, 0);
                acc[1][ni] = __builtin_amdgcn_mfma_f32_16x16x32_bf16(a1, bfr, acc[1][ni], 0, 0, 0);
            }
        }
        __syncthreads();
    }

    #pragma unroll
    for (int mi = 0; mi < 2; ++mi)
        #pragma unroll
        for (int ni = 0; ni < 16; ++ni)
            #pragma unroll
            for (int r = 0; r < 4; ++r) {
                int v = (mi << 4) + ((lane >> 4) << 2) + r;
                if (v < NV) {
                    int i = (ni << 4) + (lane & 15);
                    Hf[cp * 36864 + (cf * NV + v) * 256 + i] = f2bf(acc[mi][ni][r]);
                }
            }
    if (cf == 7)
        for (int j = tid; j < 2048; j += 256)
            Hf[cp * 36864 + 136 * 256 + j] = 0;
}

// ---------------------------------------------------------------------------
// Fused stage1+stage0 (verified r12 version, tables loaded up-front): per
// (n, c') bucket, tiles of 64 gathered x1 rows: C[64][136] = x1[gathered] @
// Hf[c']^T; += K1 + embL gathers; write out rows (n*4096+d)*136.
// dyn LDS 69632: dbuf 2x26624 | embLs@53248 | K1s@68608 | Ds@69184.
// ---------------------------------------------------------------------------
__global__ __launch_bounds__(256) void fused_out(
    const ushort* __restrict__ X1, const ushort* __restrict__ Hf,
    const float* __restrict__ embLp, const float* __restrict__ K1f,
    const int* __restrict__ packT, const int* __restrict__ cnt1,
    const int* __restrict__ pos, float* __restrict__ out)
{
    extern __shared__ __align__(16) char smem[];

    const int tid  = threadIdx.x;
    const int lane = tid & 63, wv = tid >> 6;
    const int bb = blockIdx.x;            // n*8 + c'
    const int n  = bb >> 3, cp = bb & 7;
    const int t0 = blockIdx.y << 6;
    const int cnt = cnt1[bb];
    if (t0 >= cnt) return;
    const int cntL = min(64, cnt - t0);

    const int sub  = lane >> 3;
    const int col8 = (lane & 7) ^ sub;
    const int* pbase = packT + (bb << 10);
    int Ta = pbase[t0 + (wv << 3) + sub] & 1023;
    int Tb = pbase[t0 + ((wv + 4) << 3) + sub] & 1023;
    const ushort* ga0 = X1 + ((size_t)((n << 10) + Ta) << 8) + (col8 << 3);
    const ushort* gb0 = X1 + ((size_t)((n << 10) + Tb) << 8) + (col8 << 3);

    float* embLs = (float*)(smem + 53248);
    for (int i = tid; i < 3840; i += 256) embLs[i] = embLp[i];
    float* K1s = (float*)(smem + 68608);
    if (tid < 144) K1s[tid] = K1f[tid];
    int* Ds = (int*)(smem + 69184);
    if (tid < 64) Ds[tid] = (pbase[t0 + tid] >> 16) & 4095;

    const ushort* Hb = Hf + cp * 36864;

    __builtin_amdgcn_global_load_lds((gv_t*)ga0, (lv_t*)(smem + (wv << 10)), 16, 0, 0);
    __builtin_amdgcn_global_load_lds((gv_t*)gb0, (lv_t*)(smem + ((wv + 4) << 10)), 16, 0, 0);
    stage_tile_w(smem + 8192, Hb, 0, 0, 18, wv, 4, lane);
    __syncthreads();

    f32x4 acc[9] = {};
    for (int kt = 0; kt < 4; ++kt) {
        char* cb = smem + (kt & 1) * 26624;
        if (kt < 3) {
            char* nb = smem + ((kt + 1) & 1) * 26624;
            int k0n = (kt + 1) << 6;
            __builtin_amdgcn_global_load_lds((gv_t*)(ga0 + k0n), (lv_t*)(nb + (wv << 10)), 16, 0, 0);
            __builtin_amdgcn_global_load_lds((gv_t*)(gb0 + k0n), (lv_t*)(nb + ((wv + 4) << 10)), 16, 0, 0);
            stage_tile_w(nb + 8192, Hb, 0, k0n, 18, wv, 4, lane);
        }
        #pragma unroll
        for (int ks = 0; ks < 2; ++ks) {
            int kk = ks << 5;
            bf16x8 af = frag64(cb, wv << 4, kk, lane);
            #pragma unroll
            for (int ni = 0; ni < 9; ++ni) {
                bf16x8 bfr = frag64(cb + 8192, ni << 4, kk, lane);
                acc[ni] = __builtin_amdgcn_mfma_f32_16x16x32_bf16(af, bfr, acc[ni], 0, 0, 0);
            }
        }
        __syncthreads();
    }

    float* Cs = (float*)smem;
    #pragma unroll
    for (int ni = 0; ni < 9; ++ni) {
        int col = (ni << 4) + (lane & 15);
        if (col < 136) {
            #pragma unroll
            for (int r = 0; r < 4; ++r) {
                int row = (wv << 4) + ((lane >> 4) << 2) + r;
                Cs[row * 136 + col] = acc[ni][r];
            }
        }
    }
    __syncthreads();

    #pragma unroll
    for (int rr = 0; rr < 2; ++rr) {
        int rl = tid * 2 + rr;
        int r  = rl >> 3, c = rl & 7;
        int prow = n * SEQ + LASTOFF + (Ds[r] << 3) + c;
        const int* pp = pos + 3 * prow;
        const float* e0 = embLs +        pp[0] * 20;
        const float* e1 = embLs + 1280 + pp[1] * 20;
        const float* e2 = embLs + 2560 + pp[2] * 20;
        const float* k1 = K1s + c * 17;
        float* cr = Cs + rl * 17;
        #pragma unroll
        for (int v4 = 0; v4 < 16; v4 += 4) {
            float4 a = *(const float4*)(e0 + v4);
            float4 bq = *(const float4*)(e1 + v4);
            float4 cq = *(const float4*)(e2 + v4);
            cr[v4 + 0] += a.x + bq.x + cq.x + k1[v4 + 0];
            cr[v4 + 1] += a.y + bq.y + cq.y + k1[v4 + 1];
            cr[v4 + 2] += a.z + bq.z + cq.z + k1[v4 + 2];
            cr[v4 + 3] += a.w + bq.w + cq.w + k1[v4 + 3];
        }
        cr[16] += e0[16] + e1[16] + e2[16] + k1[16];
    }
    __syncthreads();

    for (int i4 = tid; i4 < 2176; i4 += 256) {
        int r  = (i4 * 1928) >> 16;        // i4 / 34
        int fo = i4 - r * 34;
        if (r < cntL) {
            *(float4*)(out + ((size_t)((n << 12) + Ds[r])) * 136 + (fo << 2)) =
                *(const float4*)(Cs + r * 136 + (fo << 2));
        }
    }
}

// ---------------------------------------------------------------------------
extern "C" void kernel_launch(void* const* d_in, const int* in_sizes, int n_in,
                              void* d_out, int out_size, void* d_ws, size_t ws_size,
                              hipStream_t stream)
{
    (void)in_sizes; (void)n_in; (void)out_size; (void)ws_size;
    const float* x     = (const float*)d_in[0];
    const int*   value = (const int*)d_in[1];
    const int*   pos   = (const int*)d_in[3];
    const float* W2    = (const float*)d_in[4];
    const float* b2    = (const float*)d_in[5];
    const float* W1    = (const float*)d_in[6];
    const float* b1    = (const float*)d_in[7];
    const float* W0    = (const float*)d_in[8];
    const float* b0    = (const float*)d_in[9];
    const float* emb   = (const float*)d_in[10];
    const float* lin_w = (const float*)d_in[11];
    const float* lin_b = (const float*)d_in[12];
    float* out = (float*)d_out;

    char* ws = (char*)d_ws;
    ushort* Wb2T  = (ushort*)(ws);                  // 1 MB
    ushort* W0n   = (ushort*)(ws + 2097152);        // 1 MB
    ushort* W1n   = (ushort*)(ws + 3145728);        // 1 MB
    ushort* xb    = (ushort*)(ws + 4194304);        // 1 MB
    int*    dest2 = (int*)   (ws + 5242880);        // 16384 ints
    int*    cnt1  = (int*)   (ws + 5308416);        // 64 ints
    int*    packT = (int*)   (ws + 5308672);        // 64*1024 ints = 256 KB
    ushort* x1b   = (ushort*)(ws + 5570816);        // 4 MB
    float*  embLp = (float*) (ws + 9838848);        // 3840 fp32
    ushort* Hf    = (ushort*)(ws + 9854208);        // 576 KB
    float*  K1f   = (float*) (ws + 10444032);       // 144 fp32
    // total ~10.4 MB

    prep_main<<<656, 256, 0, stream>>>(x, W2, W1, W0, lin_w, value,
                                       emb, b0, lin_b,
                                       xb, Wb2T, W1n, W0n, dest2, packT, cnt1, embLp);
    g2h<<<320, 256, 65536, stream>>>(xb, Wb2T, b2, dest2, x1b,
                                     W0n, lin_w, W1n, b1, Hf, K1f);
    fused_out<<<dim3(64, 12), 256, 69632, stream>>>(x1b, Hf, embLp, K1f,
                                                    packT, cnt1, pos, out);
}